// Round 2
// baseline (142.870 us; speedup 1.0000x reference)
//
#include <hip/hip_runtime.h>

#define N_DIM 4096

// One block (256 threads) per row. Row held in registers: 4 x float4/thread.
__global__ __launch_bounds__(256) void minfonce_kernel(
    const float* __restrict__ logits,
    const int*   __restrict__ labels,
    float*       __restrict__ out)
{
    const float SCALE = 7.3890560989306495f;   // e^2 (T = 2.0)
    const int row  = blockIdx.x;
    const int tid  = threadIdx.x;
    const int lane = tid & 63;
    const int wv   = tid >> 6;

    __shared__ float smaxv[4];
    __shared__ int   smaxi[4];
    __shared__ float ssum[4];
    __shared__ float ssub[4];
    __shared__ float sacc[4];

    const float4* rp = reinterpret_cast<const float4*>(logits + (size_t)row * N_DIM);

    // ---- pass 0: load row (coalesced float4), scale, argmax-carrying max ----
    float4 v[4];
    float lmax = -INFINITY;
    int   lidx = 0;
#pragma unroll
    for (int k = 0; k < 4; ++k) {
        float4 t = rp[tid + 256 * k];
        t.x *= SCALE; t.y *= SCALE; t.z *= SCALE; t.w *= SCALE;
        v[k] = t;
        const int c0 = (tid + 256 * k) * 4;
        if (t.x > lmax) { lmax = t.x; lidx = c0 + 0; }
        if (t.y > lmax) { lmax = t.y; lidx = c0 + 1; }
        if (t.z > lmax) { lmax = t.z; lidx = c0 + 2; }
        if (t.w > lmax) { lmax = t.w; lidx = c0 + 3; }
    }
#pragma unroll
    for (int off = 32; off > 0; off >>= 1) {
        float om = __shfl_down(lmax, off);
        int   oi = __shfl_down(lidx, off);
        if (om > lmax) { lmax = om; lidx = oi; }
    }
    if (lane == 0) { smaxv[wv] = lmax; smaxi[wv] = lidx; }
    __syncthreads();
    float M    = smaxv[0];
    int   amax = smaxi[0];
#pragma unroll
    for (int w = 1; w < 4; ++w)
        if (smaxv[w] > M) { M = smaxv[w]; amax = smaxi[w]; }

    // ---- pass 1: S_all = sum exp(s-M); S_excl = same excluding argmax elem ----
    float s_all = 0.f, s_sub = 0.f;
#pragma unroll
    for (int k = 0; k < 4; ++k) {
        const int c0 = (tid + 256 * k) * 4;
        float e;
        e = __expf(v[k].x - M); s_all += e; if (c0 + 0 != amax) s_sub += e;
        e = __expf(v[k].y - M); s_all += e; if (c0 + 1 != amax) s_sub += e;
        e = __expf(v[k].z - M); s_all += e; if (c0 + 2 != amax) s_sub += e;
        e = __expf(v[k].w - M); s_all += e; if (c0 + 3 != amax) s_sub += e;
    }
#pragma unroll
    for (int off = 32; off > 0; off >>= 1) {
        s_all += __shfl_down(s_all, off);
        s_sub += __shfl_down(s_sub, off);
    }
    if (lane == 0) { ssum[wv] = s_all; ssub[wv] = s_sub; }
    __syncthreads();
    const float S    = ssum[0] + ssum[1] + ssum[2] + ssum[3];
    const float Ssub = ssub[0] + ssub[1] + ssub[2] + ssub[3];
    const float logS = logf(S);

    // ---- pass 2: loss terms ----
    // diag:                acc += (s_ii - M) - logS                    (= log p_ii)
    // off, label differs:
    //   j == argmax: acc += log(Ssub) - logS   (exact 1-p, no cancellation; p may ~1)
    //   else:        p = exp(u - logS) <= 1/2  -> log1p(-p) safe
    const int  li = labels[row];
    const int4* lp = reinterpret_cast<const int4*>(labels);
    float acc = 0.f;
    const float logSsub = logf(fmaxf(Ssub, 1e-37f)) - logS;
#pragma unroll
    for (int k = 0; k < 4; ++k) {
        const int4 lb = lp[tid + 256 * k];
        const int  c0 = (tid + 256 * k) * 4;

        { const int c = c0 + 0; float u = v[k].x - M;
          if (c == row) acc += u - logS;
          else if (lb.x != li) {
              if (c == amax) acc += logSsub;
              else { float p = __expf(u - logS); acc += (p > 1e-4f) ? log1pf(-p) : -p; } } }
        { const int c = c0 + 1; float u = v[k].y - M;
          if (c == row) acc += u - logS;
          else if (lb.y != li) {
              if (c == amax) acc += logSsub;
              else { float p = __expf(u - logS); acc += (p > 1e-4f) ? log1pf(-p) : -p; } } }
        { const int c = c0 + 2; float u = v[k].z - M;
          if (c == row) acc += u - logS;
          else if (lb.z != li) {
              if (c == amax) acc += logSsub;
              else { float p = __expf(u - logS); acc += (p > 1e-4f) ? log1pf(-p) : -p; } } }
        { const int c = c0 + 3; float u = v[k].w - M;
          if (c == row) acc += u - logS;
          else if (lb.w != li) {
              if (c == amax) acc += logSsub;
              else { float p = __expf(u - logS); acc += (p > 1e-4f) ? log1pf(-p) : -p; } } }
    }
#pragma unroll
    for (int off = 32; off > 0; off >>= 1)
        acc += __shfl_down(acc, off);
    if (lane == 0) sacc[wv] = acc;
    __syncthreads();
    if (tid == 0) {
        float total = sacc[0] + sacc[1] + sacc[2] + sacc[3];
        atomicAdd(out, total * (1.0f / N_DIM));
    }
}

extern "C" void kernel_launch(void* const* d_in, const int* in_sizes, int n_in,
                              void* d_out, int out_size, void* d_ws, size_t ws_size,
                              hipStream_t stream) {
    const float* logits = (const float*)d_in[0];
    const int*   labels = (const int*)d_in[1];
    float*       out    = (float*)d_out;

    // d_out is poisoned (0xAA) before every timed launch — zero it ourselves.
    hipMemsetAsync(out, 0, sizeof(float), stream);
    minfonce_kernel<<<N_DIM, 256, 0, stream>>>(logits, labels, out);
}